// Round 3
// baseline (240.569 us; speedup 1.0000x reference)
//
#include <hip/hip_runtime.h>
#include <hip/hip_bf16.h>

// Problem constants
#define NN  50000   // nodes
#define FD  128     // features
#define NE  800000  // external edges
#define NEI 400000  // internal edges
#define NG  64      // graphs

// Per-copy strides (in elements) for XCD-privatized accumulators
#define DEG_STRIDE 50176     // ints  (200704 B per copy)
#define EZ_STRIDE  8192      // floats (32768 B per copy)
#define CNT_STRIDE 64        // ints   (256 B per copy)

typedef short  short8 __attribute__((ext_vector_type(8)));
typedef float  f32x4  __attribute__((ext_vector_type(4)));

union S8 { short8 s; unsigned int u[4]; };

__device__ __forceinline__ unsigned short bf16h(float f) {
  unsigned int u = __float_as_uint(f);
  u += 0x7FFFu + ((u >> 16) & 1u);            // RNE
  return (unsigned short)(u >> 16);
}
__device__ __forceinline__ float bf16tof(unsigned short h) {
  return __uint_as_float(((unsigned int)h) << 16);
}
// packed 2xf32 -> 2xbf16 (v_cvt_pk_bf16_f32): a in low 16, b in high 16
__device__ __forceinline__ unsigned int pk_bf16(float a, float b) {
  __hip_bfloat162 h = __float22bfloat162_rn(make_float2(a, b));
  unsigned int u;
  __builtin_memcpy(&u, &h, 4);
  return u;
}
// fast reciprocal: v_rcp_f32 (~1 ulp) — tolerance is 4.2e-5, plenty of slack
__device__ __forceinline__ float frcp(float x) { return __builtin_amdgcn_rcpf(x); }

// -------------------------------------------------------------------------
// ONE aux dispatch.  R11: all atomic targets are XCD-PRIVATIZED — copy
// index = blockIdx & (ncopy-1).  Consecutive blocks land on different XCDs
// (round-robin dispatch), so each copy is touched by (mostly) one XCD and
// atomics stay L2-local instead of ping-ponging lines through the
// cross-XCD coherence point (suspected ~100 us hidden cost).
// -------------------------------------------------------------------------
#define AB_EXT 391
#define AB_INT 196
#define AB_BAT 13
#define AB_PRE 8

__global__ __launch_bounds__(256) void aux_kernel(
    const int4* __restrict__ ei4, const int4* __restrict__ iei4,
    const int* __restrict__ batch,
    const float* __restrict__ wu_e1, const float* __restrict__ wu_e2,
    const float* __restrict__ wu_i1, const float* __restrict__ wu_i2,
    int* __restrict__ deg_ext, int* __restrict__ deg_int, int* __restrict__ cnt,
    unsigned short* __restrict__ WB, float* __restrict__ wcolp, int ncopy)
{
  __shared__ float WS[64 * 129];
  __shared__ int   hb[64];
  const int b = blockIdx.x, t = threadIdx.x;
  const int cp = b & (ncopy - 1);

  if (b < AB_EXT) {
    int* __restrict__ d = deg_ext + (size_t)cp * DEG_STRIDE;
    const int base = b * 512 + t;
    #pragma unroll
    for (int u = 0; u < 2; ++u) {
      const int i = base + u * 256;
      if (i < NE / 4) {
        const int4 v = ei4[i];
        atomicAdd(&d[v.x], 1);
        atomicAdd(&d[v.y], 1);
        atomicAdd(&d[v.z], 1);
        atomicAdd(&d[v.w], 1);
      }
    }
  } else if (b < AB_EXT + AB_INT) {
    int* __restrict__ d = deg_int + (size_t)cp * DEG_STRIDE;
    const int base = (b - AB_EXT) * 512 + t;
    #pragma unroll
    for (int u = 0; u < 2; ++u) {
      const int i = base + u * 256;
      if (i < NEI / 4) {
        const int4 v = iei4[i];
        atomicAdd(&d[v.x], 1);
        atomicAdd(&d[v.y], 1);
        atomicAdd(&d[v.z], 1);
        atomicAdd(&d[v.w], 1);
      }
    }
  } else if (b < AB_EXT + AB_INT + AB_BAT) {
    if (t < 64) hb[t] = 0;
    __syncthreads();
    const int base = (b - AB_EXT - AB_INT) * 4096 + t;
    for (int u = 0; u < 16; ++u) {
      const int i = base + u * 256;
      if (i < NN) atomicAdd(&hb[batch[i]], 1);
    }
    __syncthreads();
    if (t < 64 && hb[t]) atomicAdd(&cnt[cp * CNT_STRIDE + t], hb[t]);
  } else {
    const int pb = b - AB_EXT - AB_INT - AB_BAT;   // 0..7
    const int c  = pb >> 1;                         // conv 0..3
    const int h  = pb & 1;                          // row half
    const float* wu = (c == 0) ? wu_e1 : (c == 1) ? wu_e2 : (c == 2) ? wu_i1 : wu_i2;
    for (int idx = t; idx < 64 * 129; idx += 256)
      WS[idx] = wu[(size_t)h * 64 * 129 + idx];
    __syncthreads();
    const int lane = t & 63, u = t >> 6;
    const int n = lane & 15, quad = lane >> 4;
    const int ct = 4 * h + u;
    unsigned short* wb = WB + c * 32768;
    #pragma unroll
    for (int kc = 0; kc < 4; ++kc) {
      const int k0 = kc * 32 + quad * 8;
      const float* src = &WS[(u * 16 + n) * 129 + k0];
      short8 hi, lo;
      #pragma unroll
      for (int e = 0; e < 8; ++e) {
        const float v = src[e];
        const unsigned short hh = bf16h(v);
        hi[e] = (short)hh;
        lo[e] = (short)bf16h(v - bf16tof(hh));
      }
      const int fbase = ((ct * 4 + kc) * 2) * 512 + lane * 8;
      *(short8*)&wb[fbase]       = hi;
      *(short8*)&wb[fbase + 512] = lo;
    }
    if (t < 64) wcolp[c * 128 + h * 64 + t] = WS[t * 129 + 128];
  }
}

// -------------------------------------------------------------------------
// Fused conv chain (merged ext+int, R10 structure).  R11 deltas only:
//  * deg load sums the ncopy XCD-private histograms (coalesced int loads)
//  * output scatter goes to XCD-private ez/iz copy (blockIdx & (ncopy-1))
// -------------------------------------------------------------------------
__global__ __launch_bounds__(512, 4) void conv_mfma_kernel(
    const float* __restrict__ x,
    const int* __restrict__ deg_ext, const int* __restrict__ deg_int,
    const int* __restrict__ batch,
    const unsigned short* __restrict__ WB, const float* __restrict__ wcolp,
    const float* __restrict__ bu_e1, const float* __restrict__ bu_e2,
    const float* __restrict__ bu_i1, const float* __restrict__ bu_i2,
    float* __restrict__ ez_sum, float* __restrict__ iz_sum, int ncopy)
{
  __shared__ unsigned short XT[2][8192];   // A fragments (bf16), 2 x 16 KB
  __shared__ float degsE[64];
  __shared__ float degsI[64];
  __shared__ int   bg[64];
  __shared__ float redA[64 * 8];           // [row][wave]: s1e, then s2e
  __shared__ float redB[64 * 8];           // [row][wave]: s1i, then s2i

  const int tid  = threadIdx.x;
  const int lane = tid & 63;
  const int w    = tid >> 6;        // wave = column tile 0..7
  const int n    = lane & 15;
  const int q    = lane >> 4;
  const int mbase = blockIdx.x * 64;
  const int j = w * 16 + n;         // this lane's output column
  const int cp = blockIdx.x & (ncopy - 1);

#define LOADB(CONV, BH, BL) do {                                              \
    const unsigned short* _p = WB + (CONV) * 32768 + (w * 4) * 1024 + lane * 8;\
    _Pragma("unroll")                                                          \
    for (int _kc = 0; _kc < 4; ++_kc) {                                        \
      BH[_kc] = *(const short8*)&_p[_kc * 1024];                               \
      BL[_kc] = *(const short8*)&_p[_kc * 1024 + 512];                         \
    }                                                                          \
  } while (0)

  // ---- hoist conv1 B-slices (both chains) + per-column scalars
  short8 BEh[4], BEl[4], BIh[4], BIl[4];
  LOADB(0, BEh, BEl);               // ext conv1
  LOADB(2, BIh, BIl);               // int conv1
  const float wcE1 = wcolp[0 * 128 + j], wcE2 = wcolp[1 * 128 + j];
  const float wcI1 = wcolp[2 * 128 + j], wcI2 = wcolp[3 * 128 + j];
  const float bE1 = bu_e1[j], bE2 = bu_e2[j];
  const float bI1 = bu_i1[j], bI2 = bu_i2[j];

  // ---- stage x -> bf16 A fragments in XT[0], octet-linear (conflict-free)
  #pragma unroll
  for (int u = 0; u < 2; ++u) {
    const int oct  = u * 512 + tid;          // 1024 octets
    const int frag = oct >> 6, l = oct & 63;
    const int row  = (frag >> 2) * 16 + (l & 15);
    const int k0   = (frag & 3) * 32 + (l >> 4) * 8;
    const int node = mbase + row;
    float4 a = make_float4(0.f, 0.f, 0.f, 0.f), bb = a;
    if (node < NN) {
      const float* xr = x + (size_t)node * FD + k0;
      a  = *(const float4*)xr;
      bb = *(const float4*)(xr + 4);
    }
    S8 hi;
    hi.u[0] = pk_bf16(a.x, a.y);
    hi.u[1] = pk_bf16(a.z, a.w);
    hi.u[2] = pk_bf16(bb.x, bb.y);
    hi.u[3] = pk_bf16(bb.z, bb.w);
    *(short8*)&XT[0][oct * 8] = hi.s;
  }
  if (tid < 64) {
    const int node = mbase + tid;
    const bool v = node < NN;
    int de = 0, di = 0;
    if (v) {
      for (int c = 0; c < ncopy; ++c) {
        de += deg_ext[(size_t)c * DEG_STRIDE + node];
        di += deg_int[(size_t)c * DEG_STRIDE + node];
      }
    }
    degsE[tid] = (float)de;
    degsI[tid] = (float)di;
    bg[tid]    = v ? batch[node] : 0;
  }
  __syncthreads();   // ---- barrier 1: A fragments + degs + bg visible

  // ================= conv1, both chains share each A read ================
  f32x4 aE[4], aI[4];
  #pragma unroll
  for (int rt = 0; rt < 4; ++rt) {
    aE[rt] = (f32x4){0.f, 0.f, 0.f, 0.f};
    aI[rt] = (f32x4){0.f, 0.f, 0.f, 0.f};
  }
  #pragma unroll
  for (int kc = 0; kc < 4; ++kc) {
    #pragma unroll
    for (int rt = 0; rt < 4; ++rt) {
      const short8 Ah = *(const short8*)&XT[0][((rt * 4 + kc) * 64 + lane) * 8];
      f32x4 ce = aE[rt];
      ce = __builtin_amdgcn_mfma_f32_16x16x32_bf16(Ah, BEh[kc], ce, 0, 0, 0);
      ce = __builtin_amdgcn_mfma_f32_16x16x32_bf16(Ah, BEl[kc], ce, 0, 0, 0);
      aE[rt] = ce;
      f32x4 ci = aI[rt];
      ci = __builtin_amdgcn_mfma_f32_16x16x32_bf16(Ah, BIh[kc], ci, 0, 0, 0);
      ci = __builtin_amdgcn_mfma_f32_16x16x32_bf16(Ah, BIl[kc], ci, 0, 0, 0);
      aI[rt] = ci;
    }
  }

  // ---- epilogue1 (both chains): E1 = exp(leaky(acc + b + deg*wc)), f32
  #pragma unroll
  for (int rt = 0; rt < 4; ++rt) {
    const float4 dE = *(const float4*)&degsE[rt * 16 + 4 * q];
    const float4 dI = *(const float4*)&degsI[rt * 16 + 4 * q];
    const float dEv[4] = {dE.x, dE.y, dE.z, dE.w};
    const float dIv[4] = {dI.x, dI.y, dI.z, dI.w};
    #pragma unroll
    for (int r = 0; r < 4; ++r) {
      float ve = aE[rt][r] + bE1 + dEv[r] * wcE1;
      ve = fmaxf(ve, 0.01f * ve);
      aE[rt][r] = __expf(ve);
      float vi = aI[rt][r] + bI1 + dIv[r] * wcI1;
      vi = fmaxf(vi, 0.01f * vi);
      aI[rt][r] = __expf(vi);
    }
  }

  // ---- s1 partials (exact f32): row-sum over this wave's 16 cols
  #pragma unroll
  for (int rt = 0; rt < 4; ++rt) {
    #pragma unroll
    for (int r = 0; r < 4; ++r) {
      float te = aE[rt][r], ti = aI[rt][r];
      te += __shfl_xor(te, 1); ti += __shfl_xor(ti, 1);
      te += __shfl_xor(te, 2); ti += __shfl_xor(ti, 2);
      te += __shfl_xor(te, 4); ti += __shfl_xor(ti, 4);
      te += __shfl_xor(te, 8); ti += __shfl_xor(ti, 8);
      if (n == 0) {
        redA[(rt * 16 + q * 4 + r) * 8 + w] = te;
        redB[(rt * 16 + q * 4 + r) * 8 + w] = ti;
      }
    }
  }

  // ---- pack E1 to bf16 pairs (regs); reload B for conv2 (latency hides
  //      under the pack + barrier)
  unsigned int pE[4][2], pI[4][2];
  #pragma unroll
  for (int rt = 0; rt < 4; ++rt) {
    pE[rt][0] = pk_bf16(aE[rt][0], aE[rt][1]);
    pE[rt][1] = pk_bf16(aE[rt][2], aE[rt][3]);
    pI[rt][0] = pk_bf16(aI[rt][0], aI[rt][1]);
    pI[rt][1] = pk_bf16(aI[rt][2], aI[rt][3]);
  }
  LOADB(1, BEh, BEl);               // ext conv2 (reuses B regs)
  LOADB(3, BIh, BIl);               // int conv2

  // ---- write E1e -> XT[1] in A-fragment order (no WAR: XT[1] fresh)
  #pragma unroll
  for (int rt = 0; rt < 4; ++rt) {
    const int ib = ((rt * 4 + (w >> 1)) * 64 + ((w & 1) * 2 + (n >> 3)) * 16 + q * 4) * 8 + (n & 7);
    XT[1][ib]      = (unsigned short)(pE[rt][0] & 0xFFFFu);
    XT[1][ib + 8]  = (unsigned short)(pE[rt][0] >> 16);
    XT[1][ib + 16] = (unsigned short)(pE[rt][1] & 0xFFFFu);
    XT[1][ib + 24] = (unsigned short)(pE[rt][1] >> 16);
  }
  __syncthreads();   // ---- barrier 2: XT1 + s1 partials visible; XT0 reads done

  // ---- write E1i -> XT[0] (safe now)
  #pragma unroll
  for (int rt = 0; rt < 4; ++rt) {
    const int ib = ((rt * 4 + (w >> 1)) * 64 + ((w & 1) * 2 + (n >> 3)) * 16 + q * 4) * 8 + (n & 7);
    XT[0][ib]      = (unsigned short)(pI[rt][0] & 0xFFFFu);
    XT[0][ib + 8]  = (unsigned short)(pI[rt][0] >> 16);
    XT[0][ib + 16] = (unsigned short)(pI[rt][1] & 0xFFFFu);
    XT[0][ib + 24] = (unsigned short)(pI[rt][1] >> 16);
  }

  // ---- row-owned s1 inverses: lane ℓ sums row ℓ (1 rcp per row, not 16)
  float s1iE, s1iI;
  {
    const f32x4 a0 = *(const f32x4*)&redA[lane * 8];
    const f32x4 a1 = *(const f32x4*)&redA[lane * 8 + 4];
    s1iE = frcp(((a0[0] + a0[1]) + (a0[2] + a0[3])) + ((a1[0] + a1[1]) + (a1[2] + a1[3])));
    const f32x4 b0 = *(const f32x4*)&redB[lane * 8];
    const f32x4 b1 = *(const f32x4*)&redB[lane * 8 + 4];
    s1iI = frcp(((b0[0] + b0[1]) + (b0[2] + b0[3])) + ((b1[0] + b1[1]) + (b1[2] + b1[3])));
  }

  // ================= conv2-ext from XT[1] =================
  f32x4 cE[4], cI[4];
  #pragma unroll
  for (int rt = 0; rt < 4; ++rt) cE[rt] = (f32x4){0.f, 0.f, 0.f, 0.f};
  #pragma unroll
  for (int kc = 0; kc < 4; ++kc) {
    #pragma unroll
    for (int rt = 0; rt < 4; ++rt) {
      const short8 Ah = *(const short8*)&XT[1][((rt * 4 + kc) * 64 + lane) * 8];
      f32x4 c = cE[rt];
      c = __builtin_amdgcn_mfma_f32_16x16x32_bf16(Ah, BEh[kc], c, 0, 0, 0);
      c = __builtin_amdgcn_mfma_f32_16x16x32_bf16(Ah, BEl[kc], c, 0, 0, 0);
      cE[rt] = c;
    }
  }
  __syncthreads();   // ---- barrier 3: E1i visible; redA/redB s1-reads done

  // ================= conv2-int from XT[0] =================
  #pragma unroll
  for (int rt = 0; rt < 4; ++rt) cI[rt] = (f32x4){0.f, 0.f, 0.f, 0.f};
  #pragma unroll
  for (int kc = 0; kc < 4; ++kc) {
    #pragma unroll
    for (int rt = 0; rt < 4; ++rt) {
      const short8 Ah = *(const short8*)&XT[0][((rt * 4 + kc) * 64 + lane) * 8];
      f32x4 c = cI[rt];
      c = __builtin_amdgcn_mfma_f32_16x16x32_bf16(Ah, BIh[kc], c, 0, 0, 0);
      c = __builtin_amdgcn_mfma_f32_16x16x32_bf16(Ah, BIl[kc], c, 0, 0, 0);
      cI[rt] = c;
    }
  }

  // ---- epilogue2 (both chains): logits = U2*inv_s1 + b + deg*wc;
  //      E2 = exp(leaky(.)); s2 partials -> redA/redB (safe after b3)
  #pragma unroll
  for (int rt = 0; rt < 4; ++rt) {
    const float4 dE = *(const float4*)&degsE[rt * 16 + 4 * q];
    const float4 dI = *(const float4*)&degsI[rt * 16 + 4 * q];
    const float dEv[4] = {dE.x, dE.y, dE.z, dE.w};
    const float dIv[4] = {dI.x, dI.y, dI.z, dI.w};
    #pragma unroll
    for (int r = 0; r < 4; ++r) {
      const int row = rt * 16 + q * 4 + r;
      const float i1e = __shfl(s1iE, row);
      const float i1i = __shfl(s1iI, row);
      float ue = cE[rt][r] * i1e + bE2 + dEv[r] * wcE2;
      ue = fmaxf(ue, 0.01f * ue);
      cE[rt][r] = __expf(ue);
      float ui = cI[rt][r] * i1i + bI2 + dIv[r] * wcI2;
      ui = fmaxf(ui, 0.01f * ui);
      cI[rt][r] = __expf(ui);
    }
    #pragma unroll
    for (int r = 0; r < 4; ++r) {
      float te = cE[rt][r], ti = cI[rt][r];
      te += __shfl_xor(te, 1); ti += __shfl_xor(ti, 1);
      te += __shfl_xor(te, 2); ti += __shfl_xor(ti, 2);
      te += __shfl_xor(te, 4); ti += __shfl_xor(ti, 4);
      te += __shfl_xor(te, 8); ti += __shfl_xor(ti, 8);
      if (n == 0) {
        redA[(rt * 16 + q * 4 + r) * 8 + w] = te;
        redB[(rt * 16 + q * 4 + r) * 8 + w] = ti;
      }
    }
  }
  __syncthreads();   // ---- barrier 4: s2 partials visible

  // ---- row-owned s2 inverses + normalize
  float s2iE, s2iI;
  {
    const f32x4 a0 = *(const f32x4*)&redA[lane * 8];
    const f32x4 a1 = *(const f32x4*)&redA[lane * 8 + 4];
    s2iE = frcp(((a0[0] + a0[1]) + (a0[2] + a0[3])) + ((a1[0] + a1[1]) + (a1[2] + a1[3])));
    const f32x4 b0 = *(const f32x4*)&redB[lane * 8];
    const f32x4 b1 = *(const f32x4*)&redB[lane * 8 + 4];
    s2iI = frcp(((b0[0] + b0[1]) + (b0[2] + b0[3])) + ((b1[0] + b1[1]) + (b1[2] + b1[3])));
  }
  #pragma unroll
  for (int rt = 0; rt < 4; ++rt) {
    #pragma unroll
    for (int r = 0; r < 4; ++r) {
      const int row = rt * 16 + q * 4 + r;
      cE[rt][r] *= __shfl(s2iE, row);
      cI[rt][r] *= __shfl(s2iI, row);
    }
  }

  // ---- scatter into XCD-private per-graph sums (batch sorted: fast path)
  {
    float* __restrict__ ezp = ez_sum + (size_t)cp * EZ_STRIDE;
    float* __restrict__ izp = iz_sum + (size_t)cp * EZ_STRIDE;
    bool fast = false; int gall = 0;
    if (mbase + 63 < NN) { gall = bg[0]; fast = (bg[63] == gall); }
    if (fast) {
      float se = 0.f, si = 0.f;
      #pragma unroll
      for (int rt = 0; rt < 4; ++rt)
        #pragma unroll
        for (int r = 0; r < 4; ++r) { se += cE[rt][r]; si += cI[rt][r]; }
      se += __shfl_xor(se, 16); si += __shfl_xor(si, 16);
      se += __shfl_xor(se, 32); si += __shfl_xor(si, 32);
      if (q == 0) {
        atomicAdd(&ezp[gall * FD + j], se);
        atomicAdd(&izp[gall * FD + j], si);
      }
    } else {
      #pragma unroll
      for (int rt = 0; rt < 4; ++rt)
        #pragma unroll
        for (int r = 0; r < 4; ++r) {
          const int row = rt * 16 + q * 4 + r;
          if (mbase + row < NN) {
            atomicAdd(&ezp[bg[row] * FD + j], cE[rt][r]);
            atomicAdd(&izp[bg[row] * FD + j], cI[rt][r]);
          }
        }
    }
  }
#undef LOADB
}

// -------------------------------------------------------------------------
// Final MLP: 64 blocks (one per graph) x 128 threads.  Sums ncopy
// XCD-private partials for z and cnt.
// -------------------------------------------------------------------------
__global__ __launch_bounds__(128) void fc_kernel(
    const float* __restrict__ ez_sum, const float* __restrict__ iz_sum,
    const int* __restrict__ cnt,
    const float* __restrict__ fc1_w, const float* __restrict__ fc1_b,
    const float* __restrict__ fc2_w, const float* __restrict__ fc2_b,
    float* __restrict__ out, int ncopy)
{
  __shared__ float z[256];
  __shared__ float red2[2];
  const int g = blockIdx.x, t = threadIdx.x;
  int cc = 0;
  float se = 0.f, si = 0.f;
  for (int c = 0; c < ncopy; ++c) {
    cc += cnt[c * CNT_STRIDE + g];
    se += ez_sum[(size_t)c * EZ_STRIDE + g * 128 + t];
    si += iz_sum[(size_t)c * EZ_STRIDE + g * 128 + t];
  }
  const float denom = fmaxf((float)cc, 1.0f);
  z[t]       = se / denom;
  z[128 + t] = si / denom;
  __syncthreads();

  const float* wr = fc1_w + (size_t)t * 256;
  float a = fc1_b[t];
  #pragma unroll 4
  for (int c = 0; c < 256; c += 4) {
    const float4 wv = *(const float4*)(wr + c);
    a += wv.x * z[c] + wv.y * z[c + 1] + wv.z * z[c + 2] + wv.w * z[c + 3];
  }
  a = fmaxf(a, 0.f) * fc2_w[t];
  a += __shfl_xor(a, 1);
  a += __shfl_xor(a, 2);
  a += __shfl_xor(a, 4);
  a += __shfl_xor(a, 8);
  a += __shfl_xor(a, 16);
  a += __shfl_xor(a, 32);
  if ((t & 63) == 0) red2[t >> 6] = a;
  __syncthreads();
  if (t == 0) out[g] = red2[0] + red2[1] + fc2_b[0];
}

// -------------------------------------------------------------------------
extern "C" void kernel_launch(void* const* d_in, const int* in_sizes, int n_in,
                              void* d_out, int out_size, void* d_ws, size_t ws_size,
                              hipStream_t stream) {
  const float* x     = (const float*)d_in[0];
  const int4*  ei4   = (const int4*) d_in[1];   // [2,E]: first E = sources
  const int4*  iei4  = (const int4*) d_in[3];
  const int*   batch = (const int*)  d_in[5];
  const float* wu_e1 = (const float*)d_in[8];
  const float* bu_e1 = (const float*)d_in[9];
  const float* wu_e2 = (const float*)d_in[12];
  const float* bu_e2 = (const float*)d_in[13];
  const float* wu_i1 = (const float*)d_in[16];
  const float* bu_i1 = (const float*)d_in[17];
  const float* wu_i2 = (const float*)d_in[20];
  const float* bu_i2 = (const float*)d_in[21];
  const float* fc1_w = (const float*)d_in[22];
  const float* fc1_b = (const float*)d_in[23];
  const float* fc2_w = (const float*)d_in[24];
  const float* fc2_b = (const float*)d_in[25];

  // XCD-privatized layout, computed at launch; fall back to 1 copy if the
  // workspace is small.  All sizes in bytes.
  const size_t need8 = 8ull * (2 * 200704 + 2 * 32768 + 256) + 262144 + 2048;
  const int ncopy = (ws_size >= need8) ? 8 : 1;

  char* ws = (char*)d_ws;
  size_t off = 0;
  int*   deg_ext = (int*)(ws + off);  off += (size_t)ncopy * 200704;
  int*   deg_int = (int*)(ws + off);  off += (size_t)ncopy * 200704;
  float* ez      = (float*)(ws + off); off += (size_t)ncopy * 32768;
  float* iz      = (float*)(ws + off); off += (size_t)ncopy * 32768;
  int*   cnt     = (int*)(ws + off);  off += (size_t)ncopy * 256;
  const size_t zero_bytes = off;
  unsigned short* WB = (unsigned short*)(ws + off); off += 262144;
  float* wcolp   = (float*)(ws + off); off += 2048;

  hipMemsetAsync(d_ws, 0, zero_bytes, stream);

  aux_kernel<<<AB_EXT + AB_INT + AB_BAT + AB_PRE, 256, 0, stream>>>(
      ei4, iei4, batch, wu_e1, wu_e2, wu_i1, wu_i2,
      deg_ext, deg_int, cnt, WB, wcolp, ncopy);

  conv_mfma_kernel<<<dim3((NN + 63) / 64), 512, 0, stream>>>(
      x, deg_ext, deg_int, batch, WB, wcolp,
      bu_e1, bu_e2, bu_i1, bu_i2, ez, iz, ncopy);

  fc_kernel<<<NG, 128, 0, stream>>>(ez, iz, cnt, fc1_w, fc1_b, fc2_w, fc2_b,
                                    (float*)d_out, ncopy);
}

// Round 4
// 225.363 us; speedup vs baseline: 1.0675x; 1.0675x over previous
//
#include <hip/hip_runtime.h>
#include <hip/hip_bf16.h>

// Problem constants
#define NN  50000   // nodes
#define FD  128     // features
#define NE  800000  // external edges
#define NEI 400000  // internal edges
#define NG  64      // graphs

// Per-copy strides (in elements) for XCD-privatized accumulators
#define DEG_STRIDE 50176     // ints  (200704 B per copy)
#define EZ_STRIDE  8192      // floats (32768 B per copy)
#define CNT_STRIDE 64        // ints   (256 B per copy)

typedef short  short8 __attribute__((ext_vector_type(8)));
typedef float  f32x4  __attribute__((ext_vector_type(4)));

union S8 { short8 s; unsigned int u[4]; };

__device__ __forceinline__ unsigned short bf16h(float f) {
  unsigned int u = __float_as_uint(f);
  u += 0x7FFFu + ((u >> 16) & 1u);            // RNE
  return (unsigned short)(u >> 16);
}
__device__ __forceinline__ float bf16tof(unsigned short h) {
  return __uint_as_float(((unsigned int)h) << 16);
}
// packed 2xf32 -> 2xbf16 (v_cvt_pk_bf16_f32): a in low 16, b in high 16
__device__ __forceinline__ unsigned int pk_bf16(float a, float b) {
  __hip_bfloat162 h = __float22bfloat162_rn(make_float2(a, b));
  unsigned int u;
  __builtin_memcpy(&u, &h, 4);
  return u;
}
// fast reciprocal: v_rcp_f32 (~1 ulp) — tolerance is 4.2e-5, plenty of slack
__device__ __forceinline__ float frcp(float x) { return __builtin_amdgcn_rcpf(x); }

// -------------------------------------------------------------------------
// ONE aux dispatch (R11 structure).  Atomic targets XCD-privatized:
// copy = blockIdx & (ncopy-1); round-robin block->XCD dispatch keeps each
// copy (mostly) XCD-local.
// -------------------------------------------------------------------------
#define AB_EXT 391
#define AB_INT 196
#define AB_BAT 13
#define AB_PRE 8

__global__ __launch_bounds__(256) void aux_kernel(
    const int4* __restrict__ ei4, const int4* __restrict__ iei4,
    const int* __restrict__ batch,
    const float* __restrict__ wu_e1, const float* __restrict__ wu_e2,
    const float* __restrict__ wu_i1, const float* __restrict__ wu_i2,
    int* __restrict__ deg_ext, int* __restrict__ deg_int, int* __restrict__ cnt,
    unsigned short* __restrict__ WB, float* __restrict__ wcolp, int ncopy)
{
  __shared__ float WS[64 * 129];
  __shared__ int   hb[64];
  const int b = blockIdx.x, t = threadIdx.x;
  const int cp = b & (ncopy - 1);

  if (b < AB_EXT) {
    int* __restrict__ d = deg_ext + (size_t)cp * DEG_STRIDE;
    const int base = b * 512 + t;
    #pragma unroll
    for (int u = 0; u < 2; ++u) {
      const int i = base + u * 256;
      if (i < NE / 4) {
        const int4 v = ei4[i];
        atomicAdd(&d[v.x], 1);
        atomicAdd(&d[v.y], 1);
        atomicAdd(&d[v.z], 1);
        atomicAdd(&d[v.w], 1);
      }
    }
  } else if (b < AB_EXT + AB_INT) {
    int* __restrict__ d = deg_int + (size_t)cp * DEG_STRIDE;
    const int base = (b - AB_EXT) * 512 + t;
    #pragma unroll
    for (int u = 0; u < 2; ++u) {
      const int i = base + u * 256;
      if (i < NEI / 4) {
        const int4 v = iei4[i];
        atomicAdd(&d[v.x], 1);
        atomicAdd(&d[v.y], 1);
        atomicAdd(&d[v.z], 1);
        atomicAdd(&d[v.w], 1);
      }
    }
  } else if (b < AB_EXT + AB_INT + AB_BAT) {
    if (t < 64) hb[t] = 0;
    __syncthreads();
    const int base = (b - AB_EXT - AB_INT) * 4096 + t;
    for (int u = 0; u < 16; ++u) {
      const int i = base + u * 256;
      if (i < NN) atomicAdd(&hb[batch[i]], 1);
    }
    __syncthreads();
    if (t < 64 && hb[t]) atomicAdd(&cnt[cp * CNT_STRIDE + t], hb[t]);
  } else {
    const int pb = b - AB_EXT - AB_INT - AB_BAT;   // 0..7
    const int c  = pb >> 1;                         // conv 0..3
    const int h  = pb & 1;                          // row half
    const float* wu = (c == 0) ? wu_e1 : (c == 1) ? wu_e2 : (c == 2) ? wu_i1 : wu_i2;
    for (int idx = t; idx < 64 * 129; idx += 256)
      WS[idx] = wu[(size_t)h * 64 * 129 + idx];
    __syncthreads();
    const int lane = t & 63, u = t >> 6;
    const int n = lane & 15, quad = lane >> 4;
    const int ct = 4 * h + u;
    unsigned short* wb = WB + c * 32768;
    #pragma unroll
    for (int kc = 0; kc < 4; ++kc) {
      const int k0 = kc * 32 + quad * 8;
      const float* src = &WS[(u * 16 + n) * 129 + k0];
      short8 hi, lo;
      #pragma unroll
      for (int e = 0; e < 8; ++e) {
        const float v = src[e];
        const unsigned short hh = bf16h(v);
        hi[e] = (short)hh;
        lo[e] = (short)bf16h(v - bf16tof(hh));
      }
      const int fbase = ((ct * 4 + kc) * 2) * 512 + lane * 8;
      *(short8*)&wb[fbase]       = hi;
      *(short8*)&wb[fbase + 512] = lo;
    }
    if (t < 64) wcolp[c * 128 + h * 64 + t] = WS[t * 129 + 128];
  }
}

// -------------------------------------------------------------------------
// R12: tiny merge of the ncopy privatized degree histograms into ONE array
// so conv reads a single copy (undoes R11's +1.4 MB conv FETCH regression
// while keeping aux's privatized atomics).  196 blocks, ~2 us.
// degm layout: [0, DEG_STRIDE) = ext, [DEG_STRIDE, 2*DEG_STRIDE) = int.
// -------------------------------------------------------------------------
__global__ __launch_bounds__(256) void merge_deg_kernel(
    const int* __restrict__ deg_ext, const int* __restrict__ deg_int,
    int* __restrict__ degm, int ncopy)
{
  const int i = blockIdx.x * 256 + threadIdx.x;   // grid covers DEG_STRIDE
  int se = 0, si = 0;
  for (int c = 0; c < ncopy; ++c) {
    se += deg_ext[(size_t)c * DEG_STRIDE + i];
    si += deg_int[(size_t)c * DEG_STRIDE + i];
  }
  degm[i] = se;
  degm[DEG_STRIDE + i] = si;
}

// -------------------------------------------------------------------------
// Fused conv chain (merged ext+int, R10 structure).  R12 deltas:
//  * deg read from single MERGED array (2 loads, R10 cost).
//  * boundary-block scatter: per-graph masked in-register reduction —
//    loop over the <=2-3 distinct graphs the 64-node tile spans (batch
//    sorted), mask rows, shfl-reduce, ONE atomic per (graph,col,chain).
//    Replaces the 32-atomics-per-thread storm (~1M device atomics, the
//    suspected duration-setting tail; WRITE_SIZE pinned at 7.6 MB).
// -------------------------------------------------------------------------
__global__ __launch_bounds__(512, 4) void conv_mfma_kernel(
    const float* __restrict__ x,
    const int* __restrict__ degm,
    const int* __restrict__ batch,
    const unsigned short* __restrict__ WB, const float* __restrict__ wcolp,
    const float* __restrict__ bu_e1, const float* __restrict__ bu_e2,
    const float* __restrict__ bu_i1, const float* __restrict__ bu_i2,
    float* __restrict__ ez_sum, float* __restrict__ iz_sum, int ncopy)
{
  __shared__ unsigned short XT[2][8192];   // A fragments (bf16), 2 x 16 KB
  __shared__ float degsE[64];
  __shared__ float degsI[64];
  __shared__ int   bg[64];
  __shared__ float redA[64 * 8];           // [row][wave]: s1e, then s2e
  __shared__ float redB[64 * 8];           // [row][wave]: s1i, then s2i

  const int tid  = threadIdx.x;
  const int lane = tid & 63;
  const int w    = tid >> 6;        // wave = column tile 0..7
  const int n    = lane & 15;
  const int q    = lane >> 4;
  const int mbase = blockIdx.x * 64;
  const int j = w * 16 + n;         // this lane's output column
  const int cp = blockIdx.x & (ncopy - 1);

#define LOADB(CONV, BH, BL) do {                                              \
    const unsigned short* _p = WB + (CONV) * 32768 + (w * 4) * 1024 + lane * 8;\
    _Pragma("unroll")                                                          \
    for (int _kc = 0; _kc < 4; ++_kc) {                                        \
      BH[_kc] = *(const short8*)&_p[_kc * 1024];                               \
      BL[_kc] = *(const short8*)&_p[_kc * 1024 + 512];                         \
    }                                                                          \
  } while (0)

  // ---- hoist conv1 B-slices (both chains) + per-column scalars
  short8 BEh[4], BEl[4], BIh[4], BIl[4];
  LOADB(0, BEh, BEl);               // ext conv1
  LOADB(2, BIh, BIl);               // int conv1
  const float wcE1 = wcolp[0 * 128 + j], wcE2 = wcolp[1 * 128 + j];
  const float wcI1 = wcolp[2 * 128 + j], wcI2 = wcolp[3 * 128 + j];
  const float bE1 = bu_e1[j], bE2 = bu_e2[j];
  const float bI1 = bu_i1[j], bI2 = bu_i2[j];

  // ---- stage x -> bf16 A fragments in XT[0], octet-linear (conflict-free)
  #pragma unroll
  for (int u = 0; u < 2; ++u) {
    const int oct  = u * 512 + tid;          // 1024 octets
    const int frag = oct >> 6, l = oct & 63;
    const int row  = (frag >> 2) * 16 + (l & 15);
    const int k0   = (frag & 3) * 32 + (l >> 4) * 8;
    const int node = mbase + row;
    float4 a = make_float4(0.f, 0.f, 0.f, 0.f), bb = a;
    if (node < NN) {
      const float* xr = x + (size_t)node * FD + k0;
      a  = *(const float4*)xr;
      bb = *(const float4*)(xr + 4);
    }
    S8 hi;
    hi.u[0] = pk_bf16(a.x, a.y);
    hi.u[1] = pk_bf16(a.z, a.w);
    hi.u[2] = pk_bf16(bb.x, bb.y);
    hi.u[3] = pk_bf16(bb.z, bb.w);
    *(short8*)&XT[0][oct * 8] = hi.s;
  }
  if (tid < 64) {
    const int node = mbase + tid;
    const bool v = node < NN;
    const int nc = v ? node : (NN - 1);
    degsE[tid] = v ? (float)degm[node] : 0.f;
    degsI[tid] = v ? (float)degm[DEG_STRIDE + node] : 0.f;
    bg[tid]    = batch[nc];       // clamped: invalid rows inherit last graph
  }
  __syncthreads();   // ---- barrier 1: A fragments + degs + bg visible

  // ================= conv1, both chains share each A read ================
  f32x4 aE[4], aI[4];
  #pragma unroll
  for (int rt = 0; rt < 4; ++rt) {
    aE[rt] = (f32x4){0.f, 0.f, 0.f, 0.f};
    aI[rt] = (f32x4){0.f, 0.f, 0.f, 0.f};
  }
  #pragma unroll
  for (int kc = 0; kc < 4; ++kc) {
    #pragma unroll
    for (int rt = 0; rt < 4; ++rt) {
      const short8 Ah = *(const short8*)&XT[0][((rt * 4 + kc) * 64 + lane) * 8];
      f32x4 ce = aE[rt];
      ce = __builtin_amdgcn_mfma_f32_16x16x32_bf16(Ah, BEh[kc], ce, 0, 0, 0);
      ce = __builtin_amdgcn_mfma_f32_16x16x32_bf16(Ah, BEl[kc], ce, 0, 0, 0);
      aE[rt] = ce;
      f32x4 ci = aI[rt];
      ci = __builtin_amdgcn_mfma_f32_16x16x32_bf16(Ah, BIh[kc], ci, 0, 0, 0);
      ci = __builtin_amdgcn_mfma_f32_16x16x32_bf16(Ah, BIl[kc], ci, 0, 0, 0);
      aI[rt] = ci;
    }
  }

  // ---- epilogue1 (both chains): E1 = exp(leaky(acc + b + deg*wc)), f32
  #pragma unroll
  for (int rt = 0; rt < 4; ++rt) {
    const float4 dE = *(const float4*)&degsE[rt * 16 + 4 * q];
    const float4 dI = *(const float4*)&degsI[rt * 16 + 4 * q];
    const float dEv[4] = {dE.x, dE.y, dE.z, dE.w};
    const float dIv[4] = {dI.x, dI.y, dI.z, dI.w};
    #pragma unroll
    for (int r = 0; r < 4; ++r) {
      float ve = aE[rt][r] + bE1 + dEv[r] * wcE1;
      ve = fmaxf(ve, 0.01f * ve);
      aE[rt][r] = __expf(ve);
      float vi = aI[rt][r] + bI1 + dIv[r] * wcI1;
      vi = fmaxf(vi, 0.01f * vi);
      aI[rt][r] = __expf(vi);
    }
  }

  // ---- s1 partials (exact f32): row-sum over this wave's 16 cols
  #pragma unroll
  for (int rt = 0; rt < 4; ++rt) {
    #pragma unroll
    for (int r = 0; r < 4; ++r) {
      float te = aE[rt][r], ti = aI[rt][r];
      te += __shfl_xor(te, 1); ti += __shfl_xor(ti, 1);
      te += __shfl_xor(te, 2); ti += __shfl_xor(ti, 2);
      te += __shfl_xor(te, 4); ti += __shfl_xor(ti, 4);
      te += __shfl_xor(te, 8); ti += __shfl_xor(ti, 8);
      if (n == 0) {
        redA[(rt * 16 + q * 4 + r) * 8 + w] = te;
        redB[(rt * 16 + q * 4 + r) * 8 + w] = ti;
      }
    }
  }

  // ---- pack E1 to bf16 pairs (regs); reload B for conv2 (latency hides
  //      under the pack + barrier)
  unsigned int pE[4][2], pI[4][2];
  #pragma unroll
  for (int rt = 0; rt < 4; ++rt) {
    pE[rt][0] = pk_bf16(aE[rt][0], aE[rt][1]);
    pE[rt][1] = pk_bf16(aE[rt][2], aE[rt][3]);
    pI[rt][0] = pk_bf16(aI[rt][0], aI[rt][1]);
    pI[rt][1] = pk_bf16(aI[rt][2], aI[rt][3]);
  }
  LOADB(1, BEh, BEl);               // ext conv2 (reuses B regs)
  LOADB(3, BIh, BIl);               // int conv2

  // ---- write E1e -> XT[1] in A-fragment order (no WAR: XT[1] fresh)
  #pragma unroll
  for (int rt = 0; rt < 4; ++rt) {
    const int ib = ((rt * 4 + (w >> 1)) * 64 + ((w & 1) * 2 + (n >> 3)) * 16 + q * 4) * 8 + (n & 7);
    XT[1][ib]      = (unsigned short)(pE[rt][0] & 0xFFFFu);
    XT[1][ib + 8]  = (unsigned short)(pE[rt][0] >> 16);
    XT[1][ib + 16] = (unsigned short)(pE[rt][1] & 0xFFFFu);
    XT[1][ib + 24] = (unsigned short)(pE[rt][1] >> 16);
  }
  __syncthreads();   // ---- barrier 2: XT1 + s1 partials visible; XT0 reads done

  // ---- write E1i -> XT[0] (safe now)
  #pragma unroll
  for (int rt = 0; rt < 4; ++rt) {
    const int ib = ((rt * 4 + (w >> 1)) * 64 + ((w & 1) * 2 + (n >> 3)) * 16 + q * 4) * 8 + (n & 7);
    XT[0][ib]      = (unsigned short)(pI[rt][0] & 0xFFFFu);
    XT[0][ib + 8]  = (unsigned short)(pI[rt][0] >> 16);
    XT[0][ib + 16] = (unsigned short)(pI[rt][1] & 0xFFFFu);
    XT[0][ib + 24] = (unsigned short)(pI[rt][1] >> 16);
  }

  // ---- row-owned s1 inverses: lane ℓ sums row ℓ (1 rcp per row, not 16)
  float s1iE, s1iI;
  {
    const f32x4 a0 = *(const f32x4*)&redA[lane * 8];
    const f32x4 a1 = *(const f32x4*)&redA[lane * 8 + 4];
    s1iE = frcp(((a0[0] + a0[1]) + (a0[2] + a0[3])) + ((a1[0] + a1[1]) + (a1[2] + a1[3])));
    const f32x4 b0 = *(const f32x4*)&redB[lane * 8];
    const f32x4 b1 = *(const f32x4*)&redB[lane * 8 + 4];
    s1iI = frcp(((b0[0] + b0[1]) + (b0[2] + b0[3])) + ((b1[0] + b1[1]) + (b1[2] + b1[3])));
  }

  // ================= conv2-ext from XT[1] =================
  f32x4 cE[4], cI[4];
  #pragma unroll
  for (int rt = 0; rt < 4; ++rt) cE[rt] = (f32x4){0.f, 0.f, 0.f, 0.f};
  #pragma unroll
  for (int kc = 0; kc < 4; ++kc) {
    #pragma unroll
    for (int rt = 0; rt < 4; ++rt) {
      const short8 Ah = *(const short8*)&XT[1][((rt * 4 + kc) * 64 + lane) * 8];
      f32x4 c = cE[rt];
      c = __builtin_amdgcn_mfma_f32_16x16x32_bf16(Ah, BEh[kc], c, 0, 0, 0);
      c = __builtin_amdgcn_mfma_f32_16x16x32_bf16(Ah, BEl[kc], c, 0, 0, 0);
      cE[rt] = c;
    }
  }
  __syncthreads();   // ---- barrier 3: E1i visible; redA/redB s1-reads done

  // ================= conv2-int from XT[0] =================
  #pragma unroll
  for (int rt = 0; rt < 4; ++rt) cI[rt] = (f32x4){0.f, 0.f, 0.f, 0.f};
  #pragma unroll
  for (int kc = 0; kc < 4; ++kc) {
    #pragma unroll
    for (int rt = 0; rt < 4; ++rt) {
      const short8 Ah = *(const short8*)&XT[0][((rt * 4 + kc) * 64 + lane) * 8];
      f32x4 c = cI[rt];
      c = __builtin_amdgcn_mfma_f32_16x16x32_bf16(Ah, BIh[kc], c, 0, 0, 0);
      c = __builtin_amdgcn_mfma_f32_16x16x32_bf16(Ah, BIl[kc], c, 0, 0, 0);
      cI[rt] = c;
    }
  }

  // ---- epilogue2 (both chains): logits = U2*inv_s1 + b + deg*wc;
  //      E2 = exp(leaky(.)); s2 partials -> redA/redB (safe after b3)
  #pragma unroll
  for (int rt = 0; rt < 4; ++rt) {
    const float4 dE = *(const float4*)&degsE[rt * 16 + 4 * q];
    const float4 dI = *(const float4*)&degsI[rt * 16 + 4 * q];
    const float dEv[4] = {dE.x, dE.y, dE.z, dE.w};
    const float dIv[4] = {dI.x, dI.y, dI.z, dI.w};
    #pragma unroll
    for (int r = 0; r < 4; ++r) {
      const int row = rt * 16 + q * 4 + r;
      const float i1e = __shfl(s1iE, row);
      const float i1i = __shfl(s1iI, row);
      float ue = cE[rt][r] * i1e + bE2 + dEv[r] * wcE2;
      ue = fmaxf(ue, 0.01f * ue);
      cE[rt][r] = __expf(ue);
      float ui = cI[rt][r] * i1i + bI2 + dIv[r] * wcI2;
      ui = fmaxf(ui, 0.01f * ui);
      cI[rt][r] = __expf(ui);
    }
    #pragma unroll
    for (int r = 0; r < 4; ++r) {
      float te = cE[rt][r], ti = cI[rt][r];
      te += __shfl_xor(te, 1); ti += __shfl_xor(ti, 1);
      te += __shfl_xor(te, 2); ti += __shfl_xor(ti, 2);
      te += __shfl_xor(te, 4); ti += __shfl_xor(ti, 4);
      te += __shfl_xor(te, 8); ti += __shfl_xor(ti, 8);
      if (n == 0) {
        redA[(rt * 16 + q * 4 + r) * 8 + w] = te;
        redB[(rt * 16 + q * 4 + r) * 8 + w] = ti;
      }
    }
  }
  __syncthreads();   // ---- barrier 4: s2 partials visible

  // ---- row-owned s2 inverses + normalize
  float s2iE, s2iI;
  {
    const f32x4 a0 = *(const f32x4*)&redA[lane * 8];
    const f32x4 a1 = *(const f32x4*)&redA[lane * 8 + 4];
    s2iE = frcp(((a0[0] + a0[1]) + (a0[2] + a0[3])) + ((a1[0] + a1[1]) + (a1[2] + a1[3])));
    const f32x4 b0 = *(const f32x4*)&redB[lane * 8];
    const f32x4 b1 = *(const f32x4*)&redB[lane * 8 + 4];
    s2iI = frcp(((b0[0] + b0[1]) + (b0[2] + b0[3])) + ((b1[0] + b1[1]) + (b1[2] + b1[3])));
  }
  #pragma unroll
  for (int rt = 0; rt < 4; ++rt) {
    #pragma unroll
    for (int r = 0; r < 4; ++r) {
      const int row = rt * 16 + q * 4 + r;
      cE[rt][r] *= __shfl(s2iE, row);
      cI[rt][r] *= __shfl(s2iI, row);
    }
  }

  // ---- scatter into XCD-private per-graph sums.  R12: per-graph masked
  //      reduction for boundary blocks (no per-element atomic storm).
  {
    float* __restrict__ ezp = ez_sum + (size_t)cp * EZ_STRIDE;
    float* __restrict__ izp = iz_sum + (size_t)cp * EZ_STRIDE;

    // zero contributions from out-of-range rows (last block only)
    if (mbase + 63 >= NN) {
      #pragma unroll
      for (int rt = 0; rt < 4; ++rt)
        #pragma unroll
        for (int r = 0; r < 4; ++r) {
          const int row = rt * 16 + q * 4 + r;
          if (mbase + row >= NN) { cE[rt][r] = 0.f; cI[rt][r] = 0.f; }
        }
    }

    const int g0 = bg[0], g1 = bg[63];
    if (g0 == g1) {
      float se = 0.f, si = 0.f;
      #pragma unroll
      for (int rt = 0; rt < 4; ++rt)
        #pragma unroll
        for (int r = 0; r < 4; ++r) { se += cE[rt][r]; si += cI[rt][r]; }
      se += __shfl_xor(se, 16); si += __shfl_xor(si, 16);
      se += __shfl_xor(se, 32); si += __shfl_xor(si, 32);
      if (q == 0) {
        atomicAdd(&ezp[g0 * FD + j], se);
        atomicAdd(&izp[g0 * FD + j], si);
      }
    } else {
      // batch sorted: tile spans [g0,g1], typically 2 graphs
      for (int g = g0; g <= g1; ++g) {
        float se = 0.f, si = 0.f;
        #pragma unroll
        for (int rt = 0; rt < 4; ++rt)
          #pragma unroll
          for (int r = 0; r < 4; ++r) {
            const int row = rt * 16 + q * 4 + r;
            const bool m = (bg[row] == g);
            se += m ? cE[rt][r] : 0.f;
            si += m ? cI[rt][r] : 0.f;
          }
        se += __shfl_xor(se, 16); si += __shfl_xor(si, 16);
        se += __shfl_xor(se, 32); si += __shfl_xor(si, 32);
        if (q == 0) {
          atomicAdd(&ezp[g * FD + j], se);
          atomicAdd(&izp[g * FD + j], si);
        }
      }
    }
  }
#undef LOADB
}

// -------------------------------------------------------------------------
// Final MLP: 64 blocks (one per graph) x 128 threads.  Sums ncopy
// XCD-private partials for z and cnt.
// -------------------------------------------------------------------------
__global__ __launch_bounds__(128) void fc_kernel(
    const float* __restrict__ ez_sum, const float* __restrict__ iz_sum,
    const int* __restrict__ cnt,
    const float* __restrict__ fc1_w, const float* __restrict__ fc1_b,
    const float* __restrict__ fc2_w, const float* __restrict__ fc2_b,
    float* __restrict__ out, int ncopy)
{
  __shared__ float z[256];
  __shared__ float red2[2];
  const int g = blockIdx.x, t = threadIdx.x;
  int cc = 0;
  float se = 0.f, si = 0.f;
  for (int c = 0; c < ncopy; ++c) {
    cc += cnt[c * CNT_STRIDE + g];
    se += ez_sum[(size_t)c * EZ_STRIDE + g * 128 + t];
    si += iz_sum[(size_t)c * EZ_STRIDE + g * 128 + t];
  }
  const float denom = fmaxf((float)cc, 1.0f);
  z[t]       = se / denom;
  z[128 + t] = si / denom;
  __syncthreads();

  const float* wr = fc1_w + (size_t)t * 256;
  float a = fc1_b[t];
  #pragma unroll 4
  for (int c = 0; c < 256; c += 4) {
    const float4 wv = *(const float4*)(wr + c);
    a += wv.x * z[c] + wv.y * z[c + 1] + wv.z * z[c + 2] + wv.w * z[c + 3];
  }
  a = fmaxf(a, 0.f) * fc2_w[t];
  a += __shfl_xor(a, 1);
  a += __shfl_xor(a, 2);
  a += __shfl_xor(a, 4);
  a += __shfl_xor(a, 8);
  a += __shfl_xor(a, 16);
  a += __shfl_xor(a, 32);
  if ((t & 63) == 0) red2[t >> 6] = a;
  __syncthreads();
  if (t == 0) out[g] = red2[0] + red2[1] + fc2_b[0];
}

// -------------------------------------------------------------------------
extern "C" void kernel_launch(void* const* d_in, const int* in_sizes, int n_in,
                              void* d_out, int out_size, void* d_ws, size_t ws_size,
                              hipStream_t stream) {
  const float* x     = (const float*)d_in[0];
  const int4*  ei4   = (const int4*) d_in[1];   // [2,E]: first E = sources
  const int4*  iei4  = (const int4*) d_in[3];
  const int*   batch = (const int*)  d_in[5];
  const float* wu_e1 = (const float*)d_in[8];
  const float* bu_e1 = (const float*)d_in[9];
  const float* wu_e2 = (const float*)d_in[12];
  const float* bu_e2 = (const float*)d_in[13];
  const float* wu_i1 = (const float*)d_in[16];
  const float* bu_i1 = (const float*)d_in[17];
  const float* wu_i2 = (const float*)d_in[20];
  const float* bu_i2 = (const float*)d_in[21];
  const float* fc1_w = (const float*)d_in[22];
  const float* fc1_b = (const float*)d_in[23];
  const float* fc2_w = (const float*)d_in[24];
  const float* fc2_b = (const float*)d_in[25];

  // Layout: [ncopy x deg_ext][ncopy x deg_int][ncopy x ez][ncopy x iz]
  //         [ncopy x cnt] | (zeroed up to here) | [degm 2x][WB][wcolp]
  const size_t need8 = 8ull * (2 * 200704 + 2 * 32768 + 256)
                     + 2 * 200704 + 262144 + 2048;
  const int ncopy = (ws_size >= need8) ? 8 : 1;

  char* ws = (char*)d_ws;
  size_t off = 0;
  int*   deg_ext = (int*)(ws + off);  off += (size_t)ncopy * 200704;
  int*   deg_int = (int*)(ws + off);  off += (size_t)ncopy * 200704;
  float* ez      = (float*)(ws + off); off += (size_t)ncopy * 32768;
  float* iz      = (float*)(ws + off); off += (size_t)ncopy * 32768;
  int*   cnt     = (int*)(ws + off);  off += (size_t)ncopy * 256;
  const size_t zero_bytes = off;
  int*   degm    = (int*)(ws + off);  off += 2 * 200704;
  unsigned short* WB = (unsigned short*)(ws + off); off += 262144;
  float* wcolp   = (float*)(ws + off); off += 2048;

  hipMemsetAsync(d_ws, 0, zero_bytes, stream);

  aux_kernel<<<AB_EXT + AB_INT + AB_BAT + AB_PRE, 256, 0, stream>>>(
      ei4, iei4, batch, wu_e1, wu_e2, wu_i1, wu_i2,
      deg_ext, deg_int, cnt, WB, wcolp, ncopy);

  merge_deg_kernel<<<DEG_STRIDE / 256, 256, 0, stream>>>(
      deg_ext, deg_int, degm, ncopy);

  conv_mfma_kernel<<<dim3((NN + 63) / 64), 512, 0, stream>>>(
      x, degm, batch, WB, wcolp,
      bu_e1, bu_e2, bu_i1, bu_i2, ez, iz, ncopy);

  fc_kernel<<<NG, 128, 0, stream>>>(ez, iz, cnt, fc1_w, fc1_b, fc2_w, fc2_b,
                                    (float*)d_out, ncopy);
}